// Round 4
// baseline (30065.375 us; speedup 1.0000x reference)
//
#include <hip/hip_runtime.h>
#include <hip/hip_bf16.h>
#include <hip/hip_fp16.h>

// BiLSTM-CRF on MI355X. B=64,T=1024,D=512,H=256,K=52.
// v3 (resubmit; round-3 bench was an infra timeout, kernel never ran).
// v3 = v2 + tag output written as float32 (harness reads the whole concatenated
// tuple as float32; int32 bits reinterpret as denormals ~ 0 -> round-2 failure).
// Pipeline: repack ; 8x { gemm_xg_chunk ; lstm_chunk } ; emissions ; vit_fwd ; vit_back.

#define B_ 64
#define T_ 1024
#define D_ 512
#define H_ 256
#define K_ 52
#define TC_ 128
#define NC_ 8

typedef _Float16 f16;
typedef __attribute__((ext_vector_type(8))) _Float16 half8;
typedef __attribute__((ext_vector_type(4))) float f32x4;

__device__ __forceinline__ float sigmoid_(float x) {
    return 1.0f / (1.0f + exp2f(-1.44269504088896340736f * x));
}
__device__ __forceinline__ float tanh_(float x) {
    return 1.0f - 2.0f / (exp2f(2.88539008177792681472f * x) + 1.0f);
}

// ---------------------------------------------------------------------------
// Repack Whh (f32 [1024][256]) into fp16 hi/lo MFMA B-fragments.
// wfrag[dir][kb][nt][lane][0:8]=hi,[8:16]=lo ; element (n,k):
//   kb=k>>5, g=(k&31)>>3, i=k&7, nt=n>>4, lane=(g<<4)|(n&15)
// Same phi(g,i)=8g+i convention used for A fragments -> A/B k-mapping consistent
// (k-sum is permutation-invariant).
// ---------------------------------------------------------------------------
__global__ __launch_bounds__(256) void repack_whh(
    const float* __restrict__ whhf, const float* __restrict__ whhb,
    f16* __restrict__ wfrag)
{
    int idx = blockIdx.x * 256 + threadIdx.x;
    if (idx >= 2 * 1024 * 256) return;
    int dir = idx >> 18;
    int e   = idx & 262143;
    int n   = e >> 8;
    int k   = e & 255;
    const float* W = dir ? whhb : whhf;
    float w  = W[n * 256 + k];
    f16 hi = (f16)w;
    f16 lo = (f16)(w - (float)hi);
    int kb = k >> 5, g = (k & 31) >> 3, i = k & 7;
    int nt = n >> 4, lane = (g << 4) | (n & 15);
    size_t base = ((((size_t)dir * 8 + kb) * 64 + nt) * 64 + lane) * 16;
    wfrag[base + i]     = hi;
    wfrag[base + 8 + i] = lo;
}

// ---------------------------------------------------------------------------
// xg chunk = X[:, t0:t0+128, :] @ Wih^T (fp32). Tile 64x64, K=512.
// Grid (128, 16, 2). Skips fully-masked 64-row tiles.
// ---------------------------------------------------------------------------
__global__ __launch_bounds__(256) void gemm_xg_chunk(
    const float* __restrict__ X, const float* __restrict__ Wf,
    const float* __restrict__ Wb, const int* __restrict__ lens,
    float* __restrict__ xgcf, float* __restrict__ xgcb, int t0f, int t0b)
{
    const int dir = blockIdx.z;
    const float* __restrict__ W = dir ? Wb : Wf;
    float* __restrict__ out     = dir ? xgcb : xgcf;
    const int t0 = dir ? t0b : t0f;
    const int rb  = blockIdx.x;
    const int b   = rb >> 1;
    const int tl0 = (rb & 1) << 6;
    const int nb  = blockIdx.y;
    if (t0 + tl0 >= lens[b]) return;

    __shared__ __align__(16) float As[32][68];
    __shared__ __align__(16) float Ws[32][68];

    const int tid = threadIdx.x;
    const int ty = tid >> 4, tx = tid & 15;
    const int r = tid & 63, q = tid >> 6;
    float acc[4][4] = {};

    const float* Xp = X + (size_t)(b * 1024 + t0 + tl0 + r) * 512 + q * 8;
    const float* Wp = W + (size_t)(nb * 64 + r) * 512 + q * 8;

    for (int k0 = 0; k0 < 512; k0 += 32) {
        f32x4 a0 = *(const f32x4*)(Xp + k0);
        f32x4 a1 = *(const f32x4*)(Xp + k0 + 4);
        f32x4 w0 = *(const f32x4*)(Wp + k0);
        f32x4 w1 = *(const f32x4*)(Wp + k0 + 4);
        __syncthreads();
        #pragma unroll
        for (int u = 0; u < 4; u++) {
            As[q * 8 + u][r]     = a0[u];
            As[q * 8 + 4 + u][r] = a1[u];
            Ws[q * 8 + u][r]     = w0[u];
            Ws[q * 8 + 4 + u][r] = w1[u];
        }
        __syncthreads();
        #pragma unroll 8
        for (int kk = 0; kk < 32; kk++) {
            f32x4 av = *(const f32x4*)&As[kk][ty * 4];
            f32x4 wv = *(const f32x4*)&Ws[kk][tx * 4];
            #pragma unroll
            for (int jr = 0; jr < 4; jr++)
                #pragma unroll
                for (int jc = 0; jc < 4; jc++)
                    acc[jr][jc] += av[jr] * wv[jc];
        }
    }
    #pragma unroll
    for (int jr = 0; jr < 4; jr++) {
        f32x4 v = { acc[jr][0], acc[jr][1], acc[jr][2], acc[jr][3] };
        *(f32x4*)(out + ((size_t)b * TC_ + tl0 + ty * 4 + jr) * 1024 + nb * 64 + tx * 4) = v;
    }
}

// ---------------------------------------------------------------------------
// Bi-LSTM recurrence, one 128-step chunk. 8 blocks = 4 groups(16 batches) x 2 dirs,
// 512 thr. Carry (h frags fp16 hi/lo, c fp32) via hstate/cstate.
// gates(16x1024) = h(16x256)@Whh^T via 3-term fp16-split MFMA.
// Wave w owns n-tiles {w+8j}: n = 16w+lm+128j -> gate q=j>>1, p=j&1, d=16w+lm+128p.
// ---------------------------------------------------------------------------
__global__ __launch_bounds__(512) void lstm_chunk(
    const float* __restrict__ xgcf, const float* __restrict__ xgcb,
    const f16* __restrict__ wfrag,
    const float* __restrict__ bihf, const float* __restrict__ bhhf,
    const float* __restrict__ bihb, const float* __restrict__ bhhb,
    const int* __restrict__ lens,
    float* __restrict__ hfo, float* __restrict__ hbo,
    float* __restrict__ cstate, f16* __restrict__ hstate,
    int t0f, int t0b, int first)
{
    const int blk = blockIdx.x;
    const int dir = blk >> 2;
    const int grp = blk & 3;
    const float* __restrict__ xg  = dir ? xgcb : xgcf;
    float* __restrict__ hout      = dir ? hbo : hfo;
    const float* __restrict__ bih = dir ? bihb : bihf;
    const float* __restrict__ bhh = dir ? bhhb : bhhf;
    const f16* __restrict__ wf    = wfrag + (size_t)dir * (8 * 64 * 64 * 16);
    const int t0 = dir ? t0b : t0f;

    const int b0 = grp * 16;
    const int maxlen = lens[b0];                  // sorted descending
    const int tend = min(t0 + TC_, maxlen);       // steps tt in [t0, tend)
    const int tid = threadIdx.x;
    const int w  = tid >> 6;
    const int l  = tid & 63;
    const int lm = l & 15;
    const int lg = l >> 4;

    __shared__ __align__(16) f16 hhi[8][64][8];   // A-frag: [kb][lane][i]
    __shared__ __align__(16) f16 hlo[8][64][8];

    half8* hsthi = (half8*)(hstate + (size_t)blk * 8192);
    half8* hstlo = hsthi + 512;
    if (first) {
        half8 z = {};
        ((half8*)hhi)[tid] = z;
        ((half8*)hlo)[tid] = z;
    } else {
        ((half8*)hhi)[tid] = hsthi[tid];
        ((half8*)hlo)[tid] = hstlo[tid];
    }

    int   mylen[4];
    float c[2][4];
    float bias[2][4];
    #pragma unroll
    for (int jb = 0; jb < 4; jb++) mylen[jb] = lens[b0 + 4 * lg + jb];
    #pragma unroll
    for (int p = 0; p < 2; p++) {
        const int d = 16 * w + lm + 128 * p;
        #pragma unroll
        for (int q = 0; q < 4; q++)
            bias[p][q] = bih[d + 256 * q] + bhh[d + 256 * q];
        #pragma unroll
        for (int jb = 0; jb < 4; jb++)
            c[p][jb] = first ? 0.f
                     : cstate[(size_t)(dir * 64 + b0 + 4 * lg + jb) * 256 + d];
    }
    __syncthreads();

    const int nsteps = tend - t0;
    for (int sidx = 0; sidx < nsteps; ++sidx) {
        const int tt = dir ? (tend - 1 - sidx) : (t0 + sidx);

        float xv[2][4][4];
        #pragma unroll
        for (int jb = 0; jb < 4; jb++) {
            const float* xr = xg + ((size_t)(b0 + 4 * lg + jb) * TC_ + (tt - t0)) * 1024;
            #pragma unroll
            for (int p = 0; p < 2; p++) {
                const int d = 16 * w + lm + 128 * p;
                #pragma unroll
                for (int q = 0; q < 4; q++)
                    xv[p][q][jb] = xr[d + 256 * q];
            }
        }

        f32x4 acc[8] = {};
        for (int kb = 0; kb < 8; ++kb) {
            half8 ah = *(const half8*)(&hhi[kb][l][0]);
            half8 al = *(const half8*)(&hlo[kb][l][0]);
            const half8* wp = ((const half8*)wf) + ((size_t)(kb * 64 + w) * 64 + l) * 2;
            half8 bh[8], bl[8];
            #pragma unroll
            for (int j = 0; j < 8; j++) {
                bh[j] = wp[(size_t)j * 1024];
                bl[j] = wp[(size_t)j * 1024 + 1];
            }
            #pragma unroll
            for (int j = 0; j < 8; j++)
                acc[j] = __builtin_amdgcn_mfma_f32_16x16x32_f16(ah, bh[j], acc[j], 0, 0, 0);
            #pragma unroll
            for (int j = 0; j < 8; j++)
                acc[j] = __builtin_amdgcn_mfma_f32_16x16x32_f16(al, bh[j], acc[j], 0, 0, 0);
            #pragma unroll
            for (int j = 0; j < 8; j++)
                acc[j] = __builtin_amdgcn_mfma_f32_16x16x32_f16(ah, bl[j], acc[j], 0, 0, 0);
        }
        __syncthreads();

        #pragma unroll
        for (int p = 0; p < 2; p++) {
            const int d = 16 * w + lm + 128 * p;
            #pragma unroll
            for (int jb = 0; jb < 4; jb++) {
                const int lb = 4 * lg + jb;
                const bool act = (tt < mylen[jb]);
                float gi = acc[0 + p][jb] + xv[p][0][jb] + bias[p][0];
                float gf = acc[2 + p][jb] + xv[p][1][jb] + bias[p][1];
                float gg = acc[4 + p][jb] + xv[p][2][jb] + bias[p][2];
                float go = acc[6 + p][jb] + xv[p][3][jb] + bias[p][3];
                float cn = sigmoid_(gf) * c[p][jb] + sigmoid_(gi) * tanh_(gg);
                float hn = sigmoid_(go) * tanh_(cn);
                if (act) {
                    c[p][jb] = cn;
                    hout[((size_t)(b0 + lb) * 1024 + tt) * 256 + d] = hn;
                    f16 hi = (f16)hn;
                    f16 lo = (f16)(hn - (float)hi);
                    const int kb = d >> 5, g = (d & 31) >> 3, i = d & 7;
                    hhi[kb][(g << 4) | lb][i] = hi;
                    hlo[kb][(g << 4) | lb][i] = lo;
                }
            }
        }
        __syncthreads();
    }

    #pragma unroll
    for (int p = 0; p < 2; p++) {
        const int d = 16 * w + lm + 128 * p;
        #pragma unroll
        for (int jb = 0; jb < 4; jb++)
            cstate[(size_t)(dir * 64 + b0 + 4 * lg + jb) * 256 + d] = c[p][jb];
    }
    hsthi[tid] = ((half8*)hhi)[tid];
    hstlo[tid] = ((half8*)hlo)[tid];
}

// ---------------------------------------------------------------------------
// Emissions: outs[b,t,:] = hf.Wtag[:,:256] + hb.Wtag[:,256:] + btag (t<len), else btag.
// 8 rows/block; Wtag^T staged in LDS in two 256-d halves (62KB LDS).
// ---------------------------------------------------------------------------
__global__ __launch_bounds__(256) void emissions(
    const float* __restrict__ hf, const float* __restrict__ hb,
    const float* __restrict__ Wtag, const float* __restrict__ btag,
    const int* __restrict__ lens, float* __restrict__ outs)
{
    const int r0  = blockIdx.x * 8;
    const int b   = r0 >> 10;
    const int t0  = r0 & 1023;
    const int len = lens[b];
    const int tid = threadIdx.x;

    if (t0 >= len) {
        for (int it = tid; it < 8 * K_; it += 256)
            outs[(size_t)r0 * K_ + it] = btag[it % K_];
        return;
    }

    __shared__ __align__(16) float WtT[256][53];  // [d][k]
    __shared__ __align__(16) float hl[8][256];

    const int wv = tid >> 6, ln = tid & 63;
    float s0 = (ln < K_) ? btag[ln] : 0.f;
    float s1 = s0;

    for (int half = 0; half < 2; ++half) {
        const float* __restrict__ hsrc = half ? hb : hf;
        for (int idx = tid; idx < K_ * 256; idx += 256) {
            int k = idx >> 8, d = idx & 255;
            WtT[d][k] = Wtag[k * 512 + half * 256 + d];
        }
        for (int i4 = tid; i4 < 8 * 64; i4 += 256) {
            int rr = i4 >> 6, cc = i4 & 63;
            *(f32x4*)&hl[rr][cc * 4] =
                *(const f32x4*)(hsrc + (size_t)(r0 + rr) * 256 + cc * 4);
        }
        __syncthreads();
        {
            int rr = wv * 2;
            if (ln < K_ && (t0 + rr) < len) {
                float a = 0.f;
                #pragma unroll 4
                for (int d = 0; d < 256; ++d) a += hl[rr][d] * WtT[d][ln];
                s0 += a;
            }
            rr = wv * 2 + 1;
            if (ln < K_ && (t0 + rr) < len) {
                float a = 0.f;
                #pragma unroll 4
                for (int d = 0; d < 256; ++d) a += hl[rr][d] * WtT[d][ln];
                s1 += a;
            }
        }
        __syncthreads();
    }
    if (ln < K_) {
        outs[(size_t)(r0 + wv * 2)     * K_ + ln] = s0;
        outs[(size_t)(r0 + wv * 2 + 1) * K_ + ln] = s1;
    }
}

// ---------------------------------------------------------------------------
// Viterbi forward: one wave per batch. First-occurrence argmax, reference add
// order (part[i]+trans[i][j])+e[j].
// ---------------------------------------------------------------------------
__global__ __launch_bounds__(64) void vit_fwd(
    const float* __restrict__ outs, const float* __restrict__ trans,
    const int* __restrict__ lens, unsigned char* __restrict__ bp,
    int* __restrict__ last_tag)
{
    const int b = blockIdx.x;
    const int j = threadIdx.x;
    __shared__ float tT[K_][53];   // tT[j][i] = trans[i][j]
    __shared__ float pl[64];

    for (int idx = j; idx < K_ * K_; idx += 64) {
        int i = idx / K_, jj = idx % K_;
        tT[jj][i] = trans[idx];
    }
    const int len = lens[b];
    const float* e = outs + (size_t)b * T_ * K_;
    float part = -3.4e38f;
    if (j < K_) part = e[j] + trans[50 * K_ + j];   // trans[START][j]
    pl[j] = part;
    __syncthreads();

    const float* tr = &tT[(j < K_) ? j : 0][0];
    for (int t = 1; t < len; ++t) {
        float ej = (j < K_) ? e[(size_t)t * K_ + j] : 0.f;
        float best = -3.4e38f; int bi = 0;
        #pragma unroll 4
        for (int i = 0; i < K_; i++) {
            float v = (pl[i] + tr[i]) + ej;
            if (v > best) { best = v; bi = i; }   // strict > = first occurrence
        }
        __syncthreads();
        if (j < K_) {
            pl[j] = best;
            bp[((size_t)b * T_ + t) * K_ + j] = (unsigned char)bi;
        }
        __syncthreads();
    }

    float fin = (j < K_) ? pl[j] + trans[j * K_ + 51] : -3.4e38f;  // trans[j][STOP]
    int idx = j;
    for (int off = 32; off; off >>= 1) {
        float ov = __shfl_xor(fin, off);
        int   oi = __shfl_xor(idx, off);
        if (ov > fin || (ov == fin && oi < idx)) { fin = ov; idx = oi; }
    }
    if (j == 0) last_tag[b] = idx;
}

// ---------------------------------------------------------------------------
// Viterbi backtrace: 64 lanes, one batch each. Writes tags as FLOAT (harness
// reads the whole output buffer as float32). tags[t>=len]=0.
// ---------------------------------------------------------------------------
__global__ __launch_bounds__(64) void vit_back(
    const unsigned char* __restrict__ bp, const int* __restrict__ last_tag,
    const int* __restrict__ lens, float* __restrict__ tags)
{
    const int b = threadIdx.x;
    if (b >= B_) return;
    const int len = lens[b];
    int ptr = last_tag[b];
    float* tg = tags + (size_t)b * T_;
    for (int t = len; t < T_; ++t) tg[t] = 0.0f;
    for (int t = len - 1; t >= 1; --t) {
        tg[t] = (float)ptr;
        ptr = bp[((size_t)b * T_ + t) * K_ + ptr];
    }
    tg[0] = (float)ptr;
}

// ---------------------------------------------------------------------------
extern "C" void kernel_launch(void* const* d_in, const int* in_sizes, int n_in,
                              void* d_out, int out_size, void* d_ws, size_t ws_size,
                              hipStream_t stream)
{
    const float* X     = (const float*)d_in[0];
    const int*   lens  = (const int*)  d_in[1];
    // d_in[2] = mask (derived from lens; unused)
    const float* Wihf  = (const float*)d_in[3];
    const float* Whhf  = (const float*)d_in[4];
    const float* bihf  = (const float*)d_in[5];
    const float* bhhf  = (const float*)d_in[6];
    const float* Wihb  = (const float*)d_in[7];
    const float* Whhb  = (const float*)d_in[8];
    const float* bihb  = (const float*)d_in[9];
    const float* bhhb  = (const float*)d_in[10];
    const float* Wtag  = (const float*)d_in[11];
    const float* btag  = (const float*)d_in[12];
    const float* trans = (const float*)d_in[13];

    float* outs = (float*)d_out;
    float* tags = (float*)d_out + (size_t)B_ * T_ * K_;   // float32 tag values

    // workspace layout, total ~198 MB
    char* ws = (char*)d_ws;
    float* xgcf         = (float*)(ws);                      //  33,554,432
    float* xgcb         = (float*)(ws + 33554432);           //  33,554,432
    float* hf           = (float*)(ws + 67108864);           //  67,108,864
    float* hb           = (float*)(ws + 134217728);          //  67,108,864
    f16*   wfrag        = (f16*)  (ws + 201326592);          //   2,097,152
    float* cstate       = (float*)(ws + 203423744);          //     131,072
    f16*   hstate       = (f16*)  (ws + 203554816);          //     131,072
    int*   last_tag     = (int*)  (ws + 203685888);          //       4,096
    unsigned char* bp   = (unsigned char*)(ws + 203689984);  //   3,407,872

    repack_whh<<<2048, 256, 0, stream>>>(Whhf, Whhb, wfrag);
    for (int i = 0; i < NC_; ++i) {
        const int t0f = i * TC_;
        const int t0b = (NC_ - 1 - i) * TC_;
        gemm_xg_chunk<<<dim3(128, 16, 2), 256, 0, stream>>>(
            X, Wihf, Wihb, lens, xgcf, xgcb, t0f, t0b);
        lstm_chunk<<<8, 512, 0, stream>>>(
            xgcf, xgcb, wfrag, bihf, bhhf, bihb, bhhb, lens,
            hf, hb, cstate, hstate, t0f, t0b, i == 0);
    }
    emissions<<<8192, 256, 0, stream>>>(hf, hb, Wtag, btag, lens, outs);
    vit_fwd<<<64, 64, 0, stream>>>(outs, trans, lens, bp, last_tag);
    vit_back<<<1, 64, 0, stream>>>(bp, last_tag, lens, tags);
}